// Round 4
// baseline (402.570 us; speedup 1.0000x reference)
//
#include <hip/hip_runtime.h>

#define Bn 256
#define Sn 4096
#define Fn 64
#define TCOST 0.0003f
#define INIT_CAP 500.0f

// Output layout (floats):
//   equity      : [B, S+1]        offset 0
//   positions   : [B, S+1, 3]     offset B*(S+1)
//   predictions : [B, S]          offset B*(S+1)*4
//   position_sz : [B]             offset B*(S+1)*4 + B*S
#define EQ_OFF   0
#define POS_OFF  (Bn * (Sn + 1))
#define PRED_OFF (Bn * (Sn + 1) * 4)
#define PSZ_OFF  (PRED_OFF + Bn * Sn)

// ---------------------------------------------------------------------------
// Kernel T: transpose gumbel [S, B, 3] -> [B, S, 3] (coalesced both sides).
// ---------------------------------------------------------------------------
__global__ __launch_bounds__(256) void gumbel_transpose(
    const float* __restrict__ gin,   // [S, B, 3]
    float* __restrict__ gout)        // [B, S, 3]
{
    __shared__ float tile[32 * 97];
    int s0 = (blockIdx.x & 127) * 32;
    int b0 = (blockIdx.x >> 7) * 32;

    for (int idx = threadIdx.x; idx < 32 * 96; idx += 256) {
        int i = idx / 96;
        int rem = idx - i * 96;
        tile[i * 97 + rem] = gin[(size_t)(s0 + i) * (Bn * 3) + b0 * 3 + rem];
    }
    __syncthreads();
    for (int idx = threadIdx.x; idx < 32 * 96; idx += 256) {
        int j = idx / 96;
        int rem = idx - j * 96;
        int i = rem / 3;
        int c = rem - i * 3;
        gout[(size_t)(b0 + j) * (Sn * 3) + (size_t)(s0 + i) * 3 + c] =
            tile[i * 97 + j * 3 + c];
    }
}

// ---------------------------------------------------------------------------
// Kernel A: 256 threads = 256 consecutive steps of one batch element.
// Coalesced feature dot (16 lanes/row, shuffle reduce); epilogue per thread;
// per-step equity FACTOR computed in-kernel (boundary row recomputed) and
// written to the equity slots for kernel B to scan.
// ---------------------------------------------------------------------------
__global__ __launch_bounds__(256) void trishot_fwd(
    const float* __restrict__ feat,     // [B, S, F]
    const float* __restrict__ w,        // [F]
    const float* __restrict__ p_lt, const float* __restrict__ p_st,
    const float* __restrict__ p_bps, const float* __restrict__ p_cs,
    const float* __restrict__ p_vi, const float* __restrict__ p_vct,
    const float* __restrict__ p_vst,
    const float* __restrict__ gt,       // [B, S, 3] (transposed gumbel)
    float* __restrict__ out)
{
    __shared__ float xs[256];
    __shared__ float m0s[256], v0s[256], d0s[256], r0s[256];
    __shared__ float qs[257 * 3];        // [0]=boundary probs, [t+1]=step probs

    int t = threadIdx.x;
    int R0 = blockIdx.x * 256;           // first row of this tile
    int g = t >> 4;
    int l = t & 15;

    const float LT = *p_lt, ST = *p_st, BPS = *p_bps, CS = *p_cs,
                VI = *p_vi, VCT = *p_vct, VST = *p_vst;

    float4 wv = ((const float4*)w)[l];

    int s0 = R0 & (Sn - 1);
    int b = R0 >> 12;

    // Boundary: probs of step s0-1 (or initial position if s0 == 0).
    if (t < 16) {
        if (s0 == 0) {
            if (t == 0) { qs[0] = 0.0f; qs[1] = 0.0f; qs[2] = 1.0f; }
        } else {
            float4 fv = ((const float4*)feat)[(size_t)(R0 - 1) * 16 + t];
            float partial = fmaf(fv.x, wv.x,
                            fmaf(fv.y, wv.y,
                            fmaf(fv.z, wv.z, fv.w * wv.w)));
            partial += __shfl_xor(partial, 1, 64);
            partial += __shfl_xor(partial, 2, 64);
            partial += __shfl_xor(partial, 4, 64);
            partial += __shfl_xor(partial, 8, 64);
            if (t == 0) {
                float p = 1.0f / (1.0f + __expf(-partial));
                float mom = fv.x, vix = fv.y, dvix = fv.z;
                bool collapse = (dvix < -VCT) && (vix < 30.0f);
                bool spike    = (dvix >  VST) && (vix > 20.0f);
                bool lp = ((p >= LT) && (mom > 0.0f)) || collapse;
                bool sp = ((p <= ST) && (mom < 0.0f)) || spike;
                float l0 = lp ? 1.0f : -10.0f;
                float l1 = sp ? 1.0f : -10.0f;
                float l2 = (!lp && !sp) ? 1.0f : -10.0f;
                const float* gg = gt + (size_t)(R0 - 1) * 3;
                float z0 = l0 + gg[0], z1 = l1 + gg[1], z2 = l2 + gg[2];
                float zm = fmaxf(z0, fmaxf(z1, z2));
                float e0 = __expf(z0 - zm), e1 = __expf(z1 - zm), e2 = __expf(z2 - zm);
                float inv = 1.0f / (e0 + e1 + e2);
                qs[0] = e0 * inv; qs[1] = e1 * inv; qs[2] = e2 * inv;
            }
        }
    }

    // Phase 1: dot products, 16 rows per pass, 16 passes (fully coalesced).
#pragma unroll
    for (int q = 0; q < 16; q++) {
        int row = R0 + q * 16 + g;
        float4 fv = ((const float4*)feat)[(size_t)row * 16 + l];
        float partial = fmaf(fv.x, wv.x,
                        fmaf(fv.y, wv.y,
                        fmaf(fv.z, wv.z, fv.w * wv.w)));
        partial += __shfl_xor(partial, 1, 64);
        partial += __shfl_xor(partial, 2, 64);
        partial += __shfl_xor(partial, 4, 64);
        partial += __shfl_xor(partial, 8, 64);
        if (l == 0) {
            int rr = q * 16 + g;
            xs[rr]  = partial;
            m0s[rr] = fv.x;
            v0s[rr] = fv.y;
            d0s[rr] = fv.z;
            r0s[rr] = fv.w;
        }
    }
    __syncthreads();

    // Phase 2: epilogue, one step per thread, coalesced.
    int s = s0 + t;
    float x = xs[t];
    float p = 1.0f / (1.0f + __expf(-x));
    float mom = m0s[t], vix = v0s[t], dvix = d0s[t], mret = r0s[t];

    float ss = fabsf(p - 0.5f) * 2.0f;
    bool collapse = (dvix < -VCT) && (vix < 30.0f);
    bool spike    = (dvix >  VST) && (vix > 20.0f);
    float psz = fminf(fmaxf(BPS + CS * ss, 0.2f), 1.0f);
    if (collapse || spike) psz *= (1.0f + VI);

    bool lp = ((p >= LT) && (mom > 0.0f)) || collapse;
    bool sp = ((p <= ST) && (mom < 0.0f)) || spike;
    float l0 = lp ? 1.0f : -10.0f;
    float l1 = sp ? 1.0f : -10.0f;
    float l2 = (!lp && !sp) ? 1.0f : -10.0f;

    const float* gg = gt + (size_t)(R0 + t) * 3;
    float z0 = l0 + gg[0], z1 = l1 + gg[1], z2 = l2 + gg[2];
    float zm = fmaxf(z0, fmaxf(z1, z2));
    float e0 = __expf(z0 - zm), e1 = __expf(z1 - zm), e2 = __expf(z2 - zm);
    float inv = 1.0f / (e0 + e1 + e2);
    float q0 = e0 * inv, q1 = e1 * inv, q2 = e2 * inv;

    qs[(t + 1) * 3 + 0] = q0;
    qs[(t + 1) * 3 + 1] = q1;
    qs[(t + 1) * 3 + 2] = q2;

    out[PRED_OFF + R0 + t] = p;
    float* pos = out + POS_OFF;
    size_t prow = ((size_t)b * (Sn + 1) + s + 1) * 3;
    pos[prow + 0] = q0;
    pos[prow + 1] = q1;
    pos[prow + 2] = q2;
    if (s == Sn - 1) out[PSZ_OFF + b] = psz;
    if (s == 0) {
        size_t p0row = (size_t)b * (Sn + 1) * 3;
        pos[p0row + 0] = 0.0f;
        pos[p0row + 1] = 0.0f;
        pos[p0row + 2] = 1.0f;
    }

    float rp = psz * (q0 - q1) * mret;
    __syncthreads();

    // Factor: needs previous step's probs from LDS.
    float pm0 = qs[t * 3 + 0], pm1 = qs[t * 3 + 1], pm2 = qs[t * 3 + 2];
    float pc = fabsf(q0 - pm0) + fabsf(q1 - pm1) + fabsf(q2 - pm2);
    out[EQ_OFF + (size_t)b * (Sn + 1) + s + 1] = 1.0f + rp - pc * TCOST;
}

// ---------------------------------------------------------------------------
// Kernel B: one block per batch element; prefix-product over staged factors.
// ---------------------------------------------------------------------------
#define CH 16
__global__ __launch_bounds__(256) void trishot_scan(float* __restrict__ out)
{
    int b = blockIdx.x;
    int j = threadIdx.x;
    float* eq = out + EQ_OFF + (size_t)b * (Sn + 1);

    int t0 = j * CH;
    float f[CH];
    float lprod = 1.0f;
#pragma unroll
    for (int i = 0; i < CH; i++) {
        float fac = eq[t0 + i + 1];
        f[i] = fac;
        lprod *= fac;
    }

    __shared__ float sc[256];
    sc[j] = lprod;
    __syncthreads();
#pragma unroll
    for (int off = 1; off < 256; off <<= 1) {
        float mine = sc[j];
        float other = (j >= off) ? sc[j - off] : 1.0f;
        __syncthreads();
        sc[j] = mine * other;
        __syncthreads();
    }

    float eqv = INIT_CAP * ((j > 0) ? sc[j - 1] : 1.0f);
#pragma unroll
    for (int i = 0; i < CH; i++) {
        eqv *= f[i];
        eq[t0 + i + 1] = eqv;
    }
    if (j == 0) eq[0] = INIT_CAP;
}

extern "C" void kernel_launch(void* const* d_in, const int* in_sizes, int n_in,
                              void* d_out, int out_size, void* d_ws, size_t ws_size,
                              hipStream_t stream) {
    const float* feat   = (const float*)d_in[0];
    const float* w      = (const float*)d_in[1];
    const float* lt     = (const float*)d_in[2];
    const float* st     = (const float*)d_in[3];
    const float* bps    = (const float*)d_in[4];
    const float* cs     = (const float*)d_in[5];
    const float* vi     = (const float*)d_in[6];
    const float* vct    = (const float*)d_in[7];
    const float* vst    = (const float*)d_in[8];
    const float* gumbel = (const float*)d_in[9];
    float* out = (float*)d_out;
    float* gt  = (float*)d_ws;   // 12.6 MB transposed gumbel

    gumbel_transpose<<<128 * 8, 256, 0, stream>>>(gumbel, gt);
    trishot_fwd<<<(Bn * Sn) / 256, 256, 0, stream>>>(
        feat, w, lt, st, bps, cs, vi, vct, vst, gt, out);
    trishot_scan<<<Bn, 256, 0, stream>>>(out);
}